// Round 18
// baseline (122.063 us; speedup 1.0000x reference)
//
#include <hip/hip_runtime.h>
#include <hip/hip_bf16.h>
#include <math.h>

#define T_TOKENS 4096
#define HID 512
#define INTER 2048
#define NEXP 8

typedef __bf16 bf16x8 __attribute__((ext_vector_type(8)));
typedef __bf16 bf16x4 __attribute__((ext_vector_type(4)));
typedef float f32x4 __attribute__((ext_vector_type(4)));

#define GLD16(g, l) __builtin_amdgcn_global_load_lds( \
    (const __attribute__((address_space(1))) void*)(g), \
    (__attribute__((address_space(3))) void*)(l), 16, 0, 0)

// Fast GELU (tanh form), one v_exp_f32, overflow-safe.
__device__ __forceinline__ float fast_gelu(float v) {
  float c = v * (0.7978845608028654f + 0.0356774081f * v * v);
  float e = __expf(2.0f * c);
  float th = 1.0f - 2.0f / (e + 1.0f);
  return 0.5f * v * (1.0f + th);
}

// ---------------- fused prologue: router (blocks 0..1023) + wu-transpose (1024..3071)
// ---------------- + wd-transpose (3072..5119). All three are independent.
__device__ __forceinline__ void transpose_tile(const float* __restrict__ in,
                                               __bf16* __restrict__ out,
                                               int R, int C, int r0, int c0,
                                               __bf16 (*tile)[68]) {
  int tid = threadIdx.x;
  int rr = tid >> 4;
  int cc = (tid & 15) * 4;
#pragma unroll
  for (int j = 0; j < 4; ++j) {
    int row = j * 16 + rr;
    float4 v = *(const float4*)(in + (size_t)(r0 + row) * C + c0 + cc);
    tile[row][cc + 0] = (__bf16)v.x;
    tile[row][cc + 1] = (__bf16)v.y;
    tile[row][cc + 2] = (__bf16)v.z;
    tile[row][cc + 3] = (__bf16)v.w;
  }
  __syncthreads();
#pragma unroll
  for (int j = 0; j < 4; ++j) {
    int orow = j * 16 + rr;
    bf16x4 o;
    o[0] = tile[cc + 0][orow];
    o[1] = tile[cc + 1][orow];
    o[2] = tile[cc + 2][orow];
    o[3] = tile[cc + 3][orow];
    *(bf16x4*)(out + (size_t)(c0 + orow) * R + r0 + cc) = o;
  }
}

__global__ void prep_kernel(const float* __restrict__ x, const float* __restrict__ wrt,
                            int* __restrict__ topi, float* __restrict__ topw,
                            int* __restrict__ cntpart, float* __restrict__ usagepart,
                            const float* __restrict__ wu, __bf16* __restrict__ wuT,
                            const float* __restrict__ wd, __bf16* __restrict__ wdT) {
  __shared__ float wsm[8 * 512];
  __shared__ float us[8];
  __shared__ int cs[8];
  __shared__ __bf16 tile[64][68];
  int bid = blockIdx.x;
  int tid = threadIdx.x;

  if (bid >= 3072) {               // wd transpose: R=INTER, C=HID
    int b = bid - 3072;
    int e = b >> 8;
    int c0 = (b & 7) * 64;
    int r0 = ((b >> 3) & 31) * 64;
    transpose_tile(wd + (size_t)e * INTER * HID, wdT + (size_t)e * INTER * HID,
                   INTER, HID, r0, c0, tile);
    return;
  }
  if (bid >= 1024) {               // wu transpose: R=HID, C=INTER
    int b = bid - 1024;
    int e = b >> 8;
    int c0 = (b & 31) * 64;
    int r0 = ((b >> 5) & 7) * 64;
    transpose_tile(wu + (size_t)e * HID * INTER, wuT + (size_t)e * HID * INTER,
                   HID, INTER, r0, c0, tile);
    return;
  }

  // router
  if (tid < 8) { us[tid] = 0.f; cs[tid] = 0; }
  for (int i = tid; i < 8 * 512; i += 256) {
    int e = i >> 9, h = i & 511;
    wsm[i] = wrt[h * 8 + e];
  }
  __syncthreads();
  int lane = tid & 63;
  int t = bid * 4 + (tid >> 6);
  const float* xt = x + (size_t)t * HID;
  float a[8];
#pragma unroll
  for (int e = 0; e < 8; ++e) a[e] = 0.f;
#pragma unroll
  for (int j = 0; j < 8; ++j) {
    float xv = xt[lane + j * 64];
#pragma unroll
    for (int e = 0; e < 8; ++e) a[e] += xv * wsm[e * 512 + lane + j * 64];
  }
#pragma unroll
  for (int off = 32; off > 0; off >>= 1) {
#pragma unroll
    for (int e = 0; e < 8; ++e) a[e] += __shfl_xor(a[e], off);
  }
  if (lane == 0) {
    float m = a[0];
#pragma unroll
    for (int e = 1; e < 8; ++e) m = fmaxf(m, a[e]);
    float p[8], s = 0.f;
#pragma unroll
    for (int e = 0; e < 8; ++e) { p[e] = expf(a[e] - m); s += p[e]; }
    float inv = 1.f / s;
#pragma unroll
    for (int e = 0; e < 8; ++e) atomicAdd(&us[e], p[e] * inv);
    int i0 = 0; float v0 = a[0];
#pragma unroll
    for (int e = 1; e < 8; ++e) if (a[e] > v0) { v0 = a[e]; i0 = e; }
    int i1 = -1; float v1 = -3.4e38f;
#pragma unroll
    for (int e = 0; e < 8; ++e) if (e != i0 && a[e] > v1) { v1 = a[e]; i1 = e; }
    float e1 = expf(v1 - v0);
    float w0 = 1.f / (1.f + e1);
    float w1 = e1 * w0;
    topi[t * 2] = i0; topi[t * 2 + 1] = i1;
    topw[t * 2] = w0; topw[t * 2 + 1] = w1;
    atomicAdd(&cs[i0], 1); atomicAdd(&cs[i1], 1);
  }
  __syncthreads();
  if (tid < 8) {
    cntpart[bid * 8 + tid] = cs[tid];
    usagepart[bid * 8 + tid] = us[tid];
  }
}

// ---------------- finalize: totals, aligned offsets, loss/usage tail, AND per-router-block
// ---------------- exclusive slot bases bbase[1024][8].
__global__ void finalize_kernel(const int* __restrict__ cntpart, const float* __restrict__ usagepart,
                                int* __restrict__ cnt, int* __restrict__ off,
                                int* __restrict__ bbase, float* __restrict__ tail) {
  __shared__ int cs[8][32];
  __shared__ float uf[8][32];
  __shared__ int cpre[8][32];
  __shared__ int ctot[8];
  __shared__ int offs[8];
  int tid = threadIdx.x;
  int e = tid >> 5, c = tid & 31;
  int s = 0; float u = 0.f;
  for (int b = c * 32; b < c * 32 + 32; ++b) {
    s += cntpart[b * 8 + e];
    u += usagepart[b * 8 + e];
  }
  cs[e][c] = s; uf[e][c] = u;
  __syncthreads();
  if (c == 0) {
    int run = 0;
#pragma unroll
    for (int cc = 0; cc < 32; ++cc) { cpre[e][cc] = run; run += cs[e][cc]; }
    ctot[e] = run;
    cnt[e] = run;
  }
  __syncthreads();
  if (tid == 0) {
    int o = 0;
    float loss = 0.f;
    for (int e2 = 0; e2 < 8; ++e2) {
      offs[e2] = o;
      off[e2] = o;
      o += (ctot[e2] + 127) & ~127;
      float uu = 0.f;
      for (int cc = 0; cc < 32; ++cc) uu += uf[e2][cc];
      uu *= (1.0f / 4096.0f);
      tail[1 + e2] = uu;
      float d = uu - 0.125f;
      loss += d * d;
    }
    tail[0] = loss;
  }
  __syncthreads();
  int base = offs[e] + cpre[e][c];
  for (int b = c * 32; b < c * 32 + 32; ++b) {
    bbase[b * 8 + e] = base;
    base += cntpart[b * 8 + e];
  }
}

// ---------------- gather: one wave per TOKEN; deterministic slots; x read once ------------
__global__ void gather_kernel(const float* __restrict__ x, const int* __restrict__ topi,
                              const float* __restrict__ topw, const int* __restrict__ bbase,
                              int* __restrict__ stok, float* __restrict__ sw,
                              __bf16* __restrict__ Xg) {
  int tid = threadIdx.x, lane = tid & 63;
  int t = blockIdx.x * 4 + (tid >> 6);
  int b = t >> 2;
  int j = t & 3;
  int slot0 = 0, slot1 = 0;
  if (lane == 0) {
    int ti[8];
#pragma unroll
    for (int q = 0; q < 8; ++q) ti[q] = topi[b * 8 + q];
    int e0 = ti[2 * j], e1 = ti[2 * j + 1];
    int r0 = 0, r1 = 0;
#pragma unroll
    for (int q = 0; q < 8; ++q) {
      if (q < 2 * j) { r0 += (ti[q] == e0); r1 += (ti[q] == e1); }
    }
    r1 += (e0 == e1);
    slot0 = bbase[b * 8 + e0] + r0;
    slot1 = bbase[b * 8 + e1] + r1;
    stok[slot0] = t; sw[slot0] = topw[2 * t];
    stok[slot1] = t; sw[slot1] = topw[2 * t + 1];
  }
  slot0 = __shfl(slot0, 0);
  slot1 = __shfl(slot1, 0);
  const float4* xs = (const float4*)(x + (size_t)t * HID);
  float4 v0 = xs[lane * 2], v1 = xs[lane * 2 + 1];
  bf16x8 o;
  o[0] = (__bf16)v0.x; o[1] = (__bf16)v0.y; o[2] = (__bf16)v0.z; o[3] = (__bf16)v0.w;
  o[4] = (__bf16)v1.x; o[5] = (__bf16)v1.y; o[6] = (__bf16)v1.z; o[7] = (__bf16)v1.w;
  *(bf16x8*)(Xg + (size_t)slot0 * HID + lane * 8) = o;
  *(bf16x8*)(Xg + (size_t)slot1 * HID + lane * 8) = o;
}

// ---------------- UP GEMM: 128x128 tile, 4 waves (2x2, 64x64 each), XCD-pinned ------------
// R2's proven inner loop (32KB LDS, BK=64, plain __syncthreads) + e=bid&7 XCD pinning.
// Halves staged bytes vs 64^2 (A panel staged by 16 n-tiles not 32; B by 8 m-tiles not 24).
// Active blocks ~1024 -> exactly 4/CU pinned. acc[4][4]=64 AGPR + ~60 VGPR fits 4 waves/EU.
// grid = 8e * (12mt * 16nt) = 1536
__launch_bounds__(256, 4)
__global__ void gemm128up(const __bf16* __restrict__ A, const __bf16* __restrict__ Ball,
                          __bf16* __restrict__ Hout,
                          const int* __restrict__ offp, const int* __restrict__ cntp) {
  int bid = blockIdx.x;
  int e = bid & 7;               // expert -> XCD pin
  int r = bid >> 3;
  int nt = r & 15;               // 16 n-tiles (N=2048)
  int mt = r >> 4;               // 12 m-tile capacity (128-row tiles)
  int cnte = cntp[e];
  if (mt * 128 >= cnte) return;
  int offe = offp[e];
  int m0 = offe + mt * 128;
  int n0 = nt * 128;
  const __bf16* B = Ball + (size_t)e * INTER * HID;

  __shared__ char smem[32768];   // 16KB A (128x64 bf16) + 16KB B
  char* As = smem;
  char* Bs = smem + 16384;

  int tid = threadIdx.x;
  int lane = tid & 63;
  int wid = tid >> 6;
  int wr = wid >> 1, wc = wid & 1;   // 2x2 waves, 64x64 out each

  f32x4 acc[4][4];
#pragma unroll
  for (int i = 0; i < 4; ++i)
#pragma unroll
    for (int j = 0; j < 4; ++j) acc[i][j] = (f32x4){0.f, 0.f, 0.f, 0.f};

  for (int it = 0; it < 8; ++it) {
    int k0 = it * 64;
#pragma unroll
    for (int q = 0; q < 4; ++q) {
      int L = q * 4096 + tid * 16;
      int row = L >> 7;
      int kb = L & 127;
      int kbs = kb ^ ((row & 7) << 4);   // inverse-swizzled global source, linear LDS dest
      GLD16((const char*)(A + (size_t)(m0 + row) * HID + k0) + kbs, As + L);
      GLD16((const char*)(B + (size_t)(n0 + row) * HID + k0) + kbs, Bs + L);
    }
    __syncthreads();
#pragma unroll
    for (int ks = 0; ks < 2; ++ks) {
      bf16x8 av[4], bv[4];
      int kb = ks * 64 + ((lane >> 4) << 4);
#pragma unroll
      for (int i = 0; i < 4; ++i) {
        int rowA = wr * 64 + i * 16 + (lane & 15);
        av[i] = *(const bf16x8*)(As + rowA * 128 + (kb ^ ((rowA & 7) << 4)));
        int rowB = wc * 64 + i * 16 + (lane & 15);
        bv[i] = *(const bf16x8*)(Bs + rowB * 128 + (kb ^ ((rowB & 7) << 4)));
      }
#pragma unroll
      for (int i = 0; i < 4; ++i)
#pragma unroll
        for (int j = 0; j < 4; ++j)
          acc[i][j] = __builtin_amdgcn_mfma_f32_16x16x32_bf16(av[i], bv[j], acc[i][j], 0, 0, 0);
    }
    __syncthreads();
  }

  int lim = offe + cnte;
#pragma unroll
  for (int i = 0; i < 4; ++i) {
#pragma unroll
    for (int r2 = 0; r2 < 4; ++r2) {
      int slot = m0 + wr * 64 + i * 16 + ((lane >> 4) << 2) + r2;
      if (slot < lim) {
        __bf16* hp = Hout + (size_t)slot * INTER + n0 + wc * 64 + (lane & 15);
#pragma unroll
        for (int j = 0; j < 4; ++j) {
          hp[j * 16] = (__bf16)fast_gelu(acc[i][j][r2]);
        }
      }
    }
  }
}

// ---------------- DOWN GEMM: exact R17 recipe (64x64, BK=64, full K=2048, XCD-pinned) -----
__launch_bounds__(256, 8)
__global__ void gemm_down(const __bf16* __restrict__ A, const __bf16* __restrict__ Ball,
                          float* __restrict__ Out,
                          const int* __restrict__ stok, const float* __restrict__ sw,
                          const int* __restrict__ offp, const int* __restrict__ cntp) {
  int bid = blockIdx.x;
  int e = bid & 7;               // expert -> XCD pin
  int r = bid >> 3;
  int n0 = (r & 7) * 64;         // 8 n-tiles (N=512), fastest
  int mt = r >> 3;               // 24 m-tile capacity
  int cnte = cntp[e];
  if (mt * 64 >= cnte) return;
  int offe = offp[e];
  int m0 = offe + mt * 64;
  const __bf16* B = Ball + (size_t)e * INTER * HID;

  __shared__ char smem[16384];
  char* As = smem;
  char* Bs = smem + 8192;

  int tid = threadIdx.x;
  int lane = tid & 63;
  int wid = tid >> 6;
  int wr = wid >> 1, wc = wid & 1;

  f32x4 acc[2][2];
#pragma unroll
  for (int i = 0; i < 2; ++i)
#pragma unroll
    for (int j = 0; j < 2; ++j) acc[i][j] = (f32x4){0.f, 0.f, 0.f, 0.f};

  for (int it = 0; it < 32; ++it) {
    int k0 = it * 64;
#pragma unroll
    for (int q2 = 0; q2 < 2; ++q2) {
      int L = q2 * 4096 + tid * 16;
      int row = L >> 7;
      int kb = L & 127;
      int kbs = kb ^ ((row & 7) << 4);
      GLD16((const char*)(A + (size_t)(m0 + row) * INTER + k0) + kbs, As + L);
      GLD16((const char*)(B + (size_t)(n0 + row) * INTER + k0) + kbs, Bs + L);
    }
    __syncthreads();
#pragma unroll
    for (int ks = 0; ks < 2; ++ks) {
      bf16x8 av[2], bv[2];
      int kb = ks * 64 + ((lane >> 4) << 4);
#pragma unroll
      for (int i = 0; i < 2; ++i) {
        int rowA = wr * 32 + i * 16 + (lane & 15);
        av[i] = *(const bf16x8*)(As + rowA * 128 + (kb ^ ((rowA & 7) << 4)));
        int rowB = wc * 32 + i * 16 + (lane & 15);
        bv[i] = *(const bf16x8*)(Bs + rowB * 128 + (kb ^ ((rowB & 7) << 4)));
      }
#pragma unroll
      for (int i = 0; i < 2; ++i)
#pragma unroll
        for (int j = 0; j < 2; ++j)
          acc[i][j] = __builtin_amdgcn_mfma_f32_16x16x32_bf16(av[i], bv[j], acc[i][j], 0, 0, 0);
    }
    __syncthreads();
  }

  int lim = offe + cnte;
#pragma unroll
  for (int i = 0; i < 2; ++i) {
#pragma unroll
    for (int r2 = 0; r2 < 4; ++r2) {
      int slot = m0 + wr * 32 + i * 16 + ((lane >> 4) << 2) + r2;
      if (slot < lim) {
        int t = stok[slot];
        float w = sw[slot];
        float* op = Out + (size_t)t * HID + n0 + wc * 32 + (lane & 15);
#pragma unroll
        for (int j = 0; j < 2; ++j) atomicAdd(op + j * 16, w * acc[i][j][r2]);
      }
    }
  }
}

extern "C" void kernel_launch(void* const* d_in, const int* in_sizes, int n_in,
                              void* d_out, int out_size, void* d_ws, size_t ws_size,
                              hipStream_t stream) {
  const float* x   = (const float*)d_in[0];
  const float* wrt = (const float*)d_in[1];
  const float* wu  = (const float*)d_in[2];
  const float* wd  = (const float*)d_in[3];
  float* out = (float*)d_out;
  char* ws = (char*)d_ws;

  const size_t XG_OFF   = 0;
  const size_t H_OFF    = XG_OFF  + (size_t)9216 * 512 * 2;
  const size_t WUT_OFF  = H_OFF   + (size_t)9216 * 2048 * 2;
  const size_t WDT_OFF  = WUT_OFF + (size_t)8 * 512 * 2048 * 2;
  const size_t TOK_OFF  = WDT_OFF + (size_t)8 * 512 * 2048 * 2;
  const size_t SW_OFF   = TOK_OFF  + (size_t)9216 * 4;
  const size_t TOPI_OFF = SW_OFF   + (size_t)9216 * 4;
  const size_t TOPW_OFF = TOPI_OFF + (size_t)8192 * 4;
  const size_t BBASE_OFF = TOPW_OFF + (size_t)8192 * 4;
  const size_t CPART_OFF = BBASE_OFF + (size_t)8192 * 4;
  const size_t UPART_OFF = CPART_OFF + (size_t)8192 * 4;
  const size_t CTRL_OFF  = UPART_OFF + (size_t)8192 * 4;

  __bf16* Xg   = (__bf16*)(ws + XG_OFF);
  __bf16* H    = (__bf16*)(ws + H_OFF);
  __bf16* wuT  = (__bf16*)(ws + WUT_OFF);
  __bf16* wdT  = (__bf16*)(ws + WDT_OFF);
  int*    stok = (int*)(ws + TOK_OFF);
  float*  sw   = (float*)(ws + SW_OFF);
  int*    topi = (int*)(ws + TOPI_OFF);
  float*  topw = (float*)(ws + TOPW_OFF);
  int*    bbase = (int*)(ws + BBASE_OFF);
  int*    cntpart = (int*)(ws + CPART_OFF);
  float*  usagepart = (float*)(ws + UPART_OFF);
  int*    cnt  = (int*)(ws + CTRL_OFF);
  int*    off  = (int*)(ws + CTRL_OFF + 64);

  hipMemsetAsync(d_out, 0, (size_t)T_TOKENS * HID * 4, stream);

  // fused: router (1024) + wu transpose (2048) + wd transpose (2048)
  prep_kernel<<<5120, 256, 0, stream>>>(x, wrt, topi, topw, cntpart, usagepart,
                                        wu, wuT, wd, wdT);
  finalize_kernel<<<1, 256, 0, stream>>>(cntpart, usagepart, cnt, off, bbase,
                                         out + (size_t)T_TOKENS * HID);
  gather_kernel<<<1024, 256, 0, stream>>>(x, topi, topw, bbase, stok, sw, Xg);

  // up: h = gelu(Xg @ wuT^T); 128^2 tile, grid = 8e * (12mt * 16nt) = 1536 (XCD-pinned)
  gemm128up<<<1536, 256, 0, stream>>>(Xg, wuT, H, off, cnt);
  // down: out += w*(h @ wdT^T); 64^2 tile, grid = 8e * (8nt * 24mt) = 1536, full K
  gemm_down<<<1536, 256, 0, stream>>>(H, wdT, out, stok, sw, off, cnt);
}